// Round 10
// baseline (154.313 us; speedup 1.0000x reference)
//
#include <hip/hip_runtime.h>

#define TT  200
#define IN  5
#define NH  32
#define FC1 20
#define CH  64        // h20 chunk length (= wave size)
#define RS  12        // h20 chunk row stride in h2 units (48 B, 16B-aligned)
#define NG  7         // weight pair-groups per row (28 pairs, 26 used)

typedef _Float16 h2t __attribute__((ext_vector_type(2)));   // 4 B
typedef _Float16 h4t __attribute__((ext_vector_type(4)));   // 8 B
typedef _Float16 h8t __attribute__((ext_vector_type(8)));   // 16 B

#if __has_builtin(__builtin_amdgcn_fdot2)
#define FDOT2(a, b, c) __builtin_amdgcn_fdot2((a), (b), (c), false)
#else
__device__ __forceinline__ float FDOT2(h2t a, h2t b, float c) {
    return fmaf((float)a.x, (float)b.x, fmaf((float)a.y, (float)b.y, c));
}
#endif

__device__ __forceinline__ float sigm(float a) {
    return __builtin_amdgcn_rcpf(1.f + __expf(-a));
}
__device__ __forceinline__ float tanh_f(float a) {
    return fmaf(2.f, __builtin_amdgcn_rcpf(1.f + __expf(-2.f * a)), -1.f);
}

#define EXT2(dst, src, i0, i1) dst = __builtin_shufflevector(src, src, i0, i1)

// ---- prep: convert [w_ih | w_hh] rows into f16 pairs in ws ----
// u32 element index = (g*128 + row)*4 + q ; pair j = 4g+q covers combined
// dims [2j, 2j+1] of the 52-vector [w_ih(20) | w_hh(32)]; j>=26 zero pad.
__global__ __launch_bounds__(256) void prep_w(
    const float* __restrict__ w_ih, const float* __restrict__ w_hh,
    unsigned int* __restrict__ ws)
{
    const int tid = blockIdx.x * 256 + threadIdx.x;
    if (tid >= NG * 128 * 4) return;
    const int q   = tid & 3;
    const int rem = tid >> 2;
    const int row = rem & 127;
    const int g   = rem >> 7;
    const int j   = 4 * g + q;
    const int d0  = 2 * j;
    float a = 0.f, b = 0.f;
    if (d0 < FC1)      { a = w_ih[row * FC1 + d0];        b = w_ih[row * FC1 + d0 + 1]; }
    else if (d0 < 52)  { a = w_hh[row * NH + d0 - FC1];   b = w_hh[row * NH + d0 - FC1 + 1]; }
    h2t hv = { (_Float16)a, (_Float16)b };
    ws[tid] = __builtin_bit_cast(unsigned int, hv);
}

// One wave per batch element. Lane l = (u = l&31, p = l>>5).
// Lane owns rows rA = u+32p (i|f) and rB = rA+64 (g|o), full K=52, as f16
// pairs fed to v_dot2_f32_f16. Weights come PRE-CONVERTED from ws (uint4,
// lane-coalesced) -> nothing to re-convert if the scheduler sinks loads.
__global__ __attribute__((amdgpu_waves_per_eu(4, 4))) __launch_bounds__(64)
void lstm_fused(
    const float* __restrict__ x,      // [B,200,5]
    const float* __restrict__ fc1_w,  // [20,5]
    const float* __restrict__ fc1_b,  // [20]
    const unsigned int* __restrict__ wt,  // ws: f16 weight pairs
    const float* __restrict__ b_ih,   // [128]
    const float* __restrict__ b_hh,   // [128]
    const float* __restrict__ fc2_w,  // [2,32]
    const float* __restrict__ fc2_b,  // [2]
    float* __restrict__ out)          // [B,2]
{
    const int b = blockIdx.x;
    const int l = threadIdx.x;
    const int u = l & 31;
    const int p = l >> 5;

    __shared__ __align__(16) h2t h20c[CH * RS];   // 3 KB
    __shared__ __align__(16) _Float16 sh_h[NH];   // 64 B

    const int rA = u + 32 * p;      // i (p=0) | f (p=1)
    const int rB = rA + 64;         // g (p=0) | o (p=1)

    // ---- load this lane's two weight rows (pre-converted f16 pairs) ----
    h2t wA[26], wB[26];
    {
        const uint4* wp = (const uint4*)wt;
        #pragma unroll
        for (int g = 0; g < NG - 1; ++g) {
            uint4 va = wp[g * 128 + rA];
            uint4 vb = wp[g * 128 + rB];
            wA[4*g+0] = __builtin_bit_cast(h2t, va.x);
            wA[4*g+1] = __builtin_bit_cast(h2t, va.y);
            wA[4*g+2] = __builtin_bit_cast(h2t, va.z);
            wA[4*g+3] = __builtin_bit_cast(h2t, va.w);
            wB[4*g+0] = __builtin_bit_cast(h2t, vb.x);
            wB[4*g+1] = __builtin_bit_cast(h2t, vb.y);
            wB[4*g+2] = __builtin_bit_cast(h2t, vb.z);
            wB[4*g+3] = __builtin_bit_cast(h2t, vb.w);
        }
        uint4 va = wp[6 * 128 + rA];
        uint4 vb = wp[6 * 128 + rB];
        wA[24] = __builtin_bit_cast(h2t, va.x);
        wA[25] = __builtin_bit_cast(h2t, va.y);
        wB[24] = __builtin_bit_cast(h2t, vb.x);
        wB[25] = __builtin_bit_cast(h2t, vb.y);
    }
    const float biasA = b_ih[rA] + b_hh[rA];
    const float biasB = b_ih[rB] + b_hh[rB];

    // second activation: tanh (p=0, g) vs sigmoid (p=1, o)
    const float An = (p == 0) ? 2.f : 1.f;
    const float Bn = (p == 0) ? -2.f : -1.f;
    const float Cn = (p == 0) ? -1.f : 0.f;

    // init h = 0
    if (l < 16) ((unsigned int*)sh_h)[l] = 0u;
    float c = 0.f;

    const float* xb = x + (size_t)b * (TT * IN);

    for (int tc = 0; tc < TT; tc += CH) {
        // ---- refill: lane l computes h20 for t = tc + l ----
        {
            const int t = tc + l;
            if (t < TT) {
                float xv[IN];
                #pragma unroll
                for (int i = 0; i < IN; ++i) xv[i] = xb[t * IN + i];
                h2t* row = h20c + (size_t)l * RS;
                #pragma unroll
                for (int j = 0; j < FC1; j += 2) {
                    float a0 = fc1_b[j], a1 = fc1_b[j + 1];
                    #pragma unroll
                    for (int i = 0; i < IN; ++i) {
                        a0 = fmaf(fc1_w[j * IN + i],       xv[i], a0);
                        a1 = fmaf(fc1_w[(j + 1) * IN + i], xv[i], a1);
                    }
                    row[j >> 1] = h2t{(_Float16)fmaxf(a0, 0.f),
                                      (_Float16)fmaxf(a1, 0.f)};
                }
            }
        }
        __syncthreads();   // once per 64 steps

        const int te = (TT - tc < CH) ? (TT - tc) : CH;
        for (int k = 0; k < te; ++k) {
            // gather xin = [h20(10 pairs) | h(16 pairs)] via uniform DS reads
            h2t xin[26];
            {
                const h2t* row = h20c + (size_t)k * RS;
                h8t r0 = *(const h8t*)(row);       // pairs 0-3
                h8t r1 = *(const h8t*)(row + 4);   // pairs 4-7
                h4t r2 = *(const h4t*)(row + 8);   // pairs 8-9
                EXT2(xin[0], r0, 0, 1);  EXT2(xin[1], r0, 2, 3);
                EXT2(xin[2], r0, 4, 5);  EXT2(xin[3], r0, 6, 7);
                EXT2(xin[4], r1, 0, 1);  EXT2(xin[5], r1, 2, 3);
                EXT2(xin[6], r1, 4, 5);  EXT2(xin[7], r1, 6, 7);
                EXT2(xin[8], r2, 0, 1);  EXT2(xin[9], r2, 2, 3);
                const h8t* hp = (const h8t*)sh_h;
                h8t h0 = hp[0], h1 = hp[1], h2 = hp[2], h3 = hp[3];
                EXT2(xin[10], h0, 0, 1); EXT2(xin[11], h0, 2, 3);
                EXT2(xin[12], h0, 4, 5); EXT2(xin[13], h0, 6, 7);
                EXT2(xin[14], h1, 0, 1); EXT2(xin[15], h1, 2, 3);
                EXT2(xin[16], h1, 4, 5); EXT2(xin[17], h1, 6, 7);
                EXT2(xin[18], h2, 0, 1); EXT2(xin[19], h2, 2, 3);
                EXT2(xin[20], h2, 4, 5); EXT2(xin[21], h2, 6, 7);
                EXT2(xin[22], h3, 0, 1); EXT2(xin[23], h3, 2, 3);
                EXT2(xin[24], h3, 4, 5); EXT2(xin[25], h3, 6, 7);
            }

            // 52 dot2, 2 chains per row
            float aA0 = biasA, aA1 = 0.f, aB0 = biasB, aB1 = 0.f;
            #pragma unroll
            for (int j = 0; j < 26; j += 2) {
                aA0 = FDOT2(wA[j],     xin[j],     aA0);
                aA1 = FDOT2(wA[j + 1], xin[j + 1], aA1);
                aB0 = FDOT2(wB[j],     xin[j],     aB0);
                aB1 = FDOT2(wB[j + 1], xin[j + 1], aB1);
            }
            const float aA = aA0 + aA1;
            const float aB = aB0 + aB1;

            // s0 = sigmoid(aA) [i|f]; s1 = tanh/sigmoid(aB) [g|o]
            const float s0 = sigm(aA);
            const float e1 = __expf(Bn * aB);
            const float s1 = fmaf(An, __builtin_amdgcn_rcpf(1.f + e1), Cn);

            // exchange with the other half (same-wave ds_bpermute, FIFO)
            const float x0 = __shfl_xor(s0, 32);
            const float x1 = __shfl_xor(s1, 32);

            // mirrored update: all lanes compute identical c / hval for dim u
            const float ig = (p == 0) ? (s0 * s1) : (x0 * x1);  // i*g
            const float fv = (p == 0) ? x0 : s0;                // f
            const float ov = (p == 0) ? x1 : s1;                // o
            c = fmaf(fv, c, ig);
            const float hval = ov * tanh_f(c);

            if (p == 0) sh_h[u] = (_Float16)hval;
            asm volatile("" ::: "memory");  // compiler fence; wave DS is FIFO
        }
    }

    // ---- fc2 on final h ----
    if (l < 2) {
        float acc = fc2_b[l];
        #pragma unroll
        for (int k = 0; k < NH; ++k)
            acc = fmaf(fc2_w[l * NH + k], (float)sh_h[k], acc);
        out[(size_t)b * 2 + l] = acc;
    }
}

extern "C" void kernel_launch(void* const* d_in, const int* in_sizes, int n_in,
                              void* d_out, int out_size, void* d_ws, size_t ws_size,
                              hipStream_t stream) {
    const float* x     = (const float*)d_in[0];
    const float* fc1_w = (const float*)d_in[1];
    const float* fc1_b = (const float*)d_in[2];
    const float* w_ih  = (const float*)d_in[3];
    const float* w_hh  = (const float*)d_in[4];
    const float* b_ih  = (const float*)d_in[5];
    const float* b_hh  = (const float*)d_in[6];
    const float* fc2_w = (const float*)d_in[7];
    const float* fc2_b = (const float*)d_in[8];
    float* out = (float*)d_out;
    unsigned int* ws = (unsigned int*)d_ws;

    const int B = in_sizes[0] / (TT * IN);
    prep_w<<<dim3((NG * 128 * 4 + 255) / 256), dim3(256), 0, stream>>>(w_ih, w_hh, ws);
    lstm_fused<<<dim3(B), dim3(64), 0, stream>>>(
        x, fc1_w, fc1_b, ws, b_ih, b_hh, fc2_w, fc2_b, out);
}